// Round 14
// baseline (627.334 us; speedup 1.0000x reference)
//
#include <hip/hip_runtime.h>
#include <hip/hip_bf16.h>
#include <stdint.h>

typedef float f32x4 __attribute__((ext_vector_type(4)));
typedef float fvec4 __attribute__((ext_vector_type(4)));
typedef short bf16x8 __attribute__((ext_vector_type(8)));

#define HALF_K 24576
#define NUMELK 49152
#define BATCH  8192
#define BM 256
#define BN 256
#define BK 64

#define VMCNT_I(n) asm volatile("s_waitcnt vmcnt(" #n ")" ::: "memory")
#define VMCNT(n) VMCNT_I(n)
#define SCHEDB   __builtin_amdgcn_sched_barrier(0)
#define SBAR     __builtin_amdgcn_s_barrier()

__device__ __forceinline__ short f2bf(float f) {
  __hip_bfloat16 h = __float2bfloat16(f);
  return __builtin_bit_cast(short, h);
}

__device__ __forceinline__ void gload_lds16(const short* g, short* l) {
  __builtin_amdgcn_global_load_lds(
      (const __attribute__((address_space(1))) unsigned*)g,
      (__attribute__((address_space(3))) unsigned*)l, 16, 0, 0);
}

// ---------------- prep: B pre-tiled + pre-swizzled bf16 ----------------
//   Bprep[KT*16384 + col*64 + ((kc ^ (col&7))<<3) + e],  k = KT*64 + kc*8 + e
__global__ __launch_bounds__(256)
void nnue_prep(const float* __restrict__ wW, const float* __restrict__ bW,
               short* __restrict__ Bprep) {
  int gid = blockIdx.x * 256 + threadIdx.x;   // grid 6144
  int KT  = gid >> 11;
  int rem = gid & 2047;
  int col = rem >> 3;
  int kc  = rem & 7;
  int kg  = KT * 64 + kc * 8;
  const float* src;
  if (col < 128) {
    src = wW + (size_t)col * NUMELK + kg;
  } else {
    int kk = (kg < HALF_K) ? (kg + HALF_K) : (kg - HALF_K);
    src = bW + (size_t)(col - 128) * NUMELK + kk;
  }
  fvec4 v0 = ((const fvec4*)src)[0];
  fvec4 v1 = ((const fvec4*)src)[1];
  bf16x8 o;
  o[0] = f2bf(v0[0]); o[1] = f2bf(v0[1]); o[2] = f2bf(v0[2]); o[3] = f2bf(v0[3]);
  o[4] = f2bf(v1[0]); o[5] = f2bf(v1[1]); o[6] = f2bf(v1[2]); o[7] = f2bf(v1[3]);
  *(bf16x8*)(Bprep + (size_t)KT * 16384 + col * 64 + ((kc ^ (col & 7)) << 3)) = o;
}

// ---------------- main GEMM: [8192 x 49152] x [49152 x 256] ----------------
// R11 wave-private-A structure + TWO-TILE-DEEP A pipeline (Little's-law test):
// 3 rotating A reg-buffers; iter n consumes A(n) (already retired -> cvt never
// waits), issues A(n+2); single counted wait vmcnt(8) per iter retires
// A(n+1)+B(n+1) while A(n+2)'s 8 loads stay in flight ACROSS the barrier.
// The vmem queue never empties: 128 KB/CU A outstanding continuously.
__global__ __launch_bounds__(512, 2)
void nnue_gemm(const float* __restrict__ white, const float* __restrict__ black,
               const short* __restrict__ Bprep, float* __restrict__ partial,
               int kchunk, int S) {
  __shared__ short B0s[BN * BK];   // 32 KB
  __shared__ short B1s[BN * BK];   // 32 KB

  const int t    = threadIdx.x;
  const int lane = t & 63;
  const int w    = t >> 6;             // wave 0..7: rows m0+32w..+31

  const int bid = blockIdx.x;          // 32*S blocks
  const int xcd = bid & 7, bi = bid >> 3;
  const int xpk = 8 / S;               // S in {1,2,4,8}
  const int ks  = xcd / xpk;
  const int mt  = (xcd % xpk) * (32 / xpk) + bi;
  const int m0  = mt * BM;
  const int k0  = ks * kchunk;
  const int KT0 = k0 / BK;

  f32x4 acc[2][16];
  const f32x4 zero = {0.f, 0.f, 0.f, 0.f};
#pragma unroll
  for (int a = 0; a < 2; ++a)
#pragma unroll
    for (int b = 0; b < 16; ++b) acc[a][b] = zero;

  const int l15 = lane & 15, l4 = lane >> 4;

  // A: lane reads row (m0+32w+l15 [+16 for mf=1]), floats [kg + s*32 + l4*8, +8)
  const size_t arow_off = (size_t)(m0 + w * 32 + l15) * HALF_K + l4 * 8;

  auto issueA = [&](fvec4* va, int kg) {       // 8 dwordx4, one K-tile
    const float* Af; int ka;
    if (kg < HALF_K) { Af = white; ka = kg; } else { Af = black; ka = kg - HALF_K; }
    const float* base = Af + arow_off + ka;
#pragma unroll
    for (int mf = 0; mf < 2; ++mf)
#pragma unroll
      for (int s = 0; s < 2; ++s) {
        const fvec4* p = (const fvec4*)(base + (size_t)mf * 16 * HALF_K + s * 32);
        va[mf * 4 + s * 2]     = p[0];
        va[mf * 4 + s * 2 + 1] = p[1];
      }
  };

  auto issueB = [&](short* dst, int KT) {      // 4 DMA instrs per wave
    const short* src = Bprep + (size_t)KT * 16384 + w * 2048 + lane * 8;
    short* d = dst + w * 2048;
#pragma unroll
    for (int j = 0; j < 4; ++j)
      gload_lds16(src + j * 512, d + j * 512);
  };

  auto compute = [&](const short* Bb, const fvec4* va) {
#pragma unroll
    for (int s = 0; s < 2; ++s) {
      bf16x8 af[2];
#pragma unroll
      for (int mf = 0; mf < 2; ++mf) {
        const fvec4 lo = va[mf * 4 + s * 2];
        const fvec4 hi = va[mf * 4 + s * 2 + 1];
        af[mf][0] = f2bf(lo[0]); af[mf][1] = f2bf(lo[1]);
        af[mf][2] = f2bf(lo[2]); af[mf][3] = f2bf(lo[3]);
        af[mf][4] = f2bf(hi[0]); af[mf][5] = f2bf(hi[1]);
        af[mf][6] = f2bf(hi[2]); af[mf][7] = f2bf(hi[3]);
      }
      const int kc = s * 4 + l4;
#pragma unroll
      for (int nf = 0; nf < 16; ++nf) {
        int col = nf * 16 + l15;
        bf16x8 bf = *(const bf16x8*)&Bb[col * 64 + ((kc ^ (col & 7)) << 3)];
        acc[0][nf] = __builtin_amdgcn_mfma_f32_16x16x32_bf16(af[0], bf, acc[0][nf], 0, 0, 0);
        acc[1][nf] = __builtin_amdgcn_mfma_f32_16x16x32_bf16(af[1], bf, acc[1][nf], 0, 0, 0);
      }
    }
  };

  const int niter = kchunk / BK;       // divisible by 6 for S in {1,2,4,8}

  fvec4 va0[8], va1[8], va2[8];

  // iterStep modes: 0 = steady (issueB(n+1), issueA(n+2), wait vmcnt(8));
  //                 1 = issueB(n+1) only, wait vmcnt(0);  2 = compute only.
  auto iterStep = [&](fvec4* vac, fvec4* van, const short* Bc, short* Bn,
                      int n, int mode) {
    if (mode == 0) {
      issueB(Bn, KT0 + n + 1);
      issueA(van, k0 + (n + 2) * BK);
    } else if (mode == 1) {
      issueB(Bn, KT0 + n + 1);
    }
    SCHEDB;
    compute(Bc, vac);                  // vac retired last iter: cvt never waits
    if (mode == 0) { VMCNT(8); SCHEDB; SBAR; SCHEDB; }
    else if (mode == 1) { VMCNT(0); SCHEDB; SBAR; SCHEDB; }
  };

  // ---- prologue: invariant "A(n+1) in flight, rest retired" at n=0
  issueB(B0s, KT0);                    // queue: B(0)4
  issueA(va0, k0);                     // +A(0)8
  issueA(va1, k0 + BK);                // +A(1)8 = 20
  VMCNT(8);                            // retire B(0)+A(0); A(1) stays in flight
  SCHEDB; SBAR; SCHEDB;

  // ---- main loop: 6-iter unroll (va phase 3 x B phase 2), full staging
  for (int g = 0; g < niter / 6 - 1; ++g) {
    const int n = g * 6;
    iterStep(va0, va2, B0s, B1s, n,     0);
    iterStep(va1, va0, B1s, B0s, n + 1, 0);
    iterStep(va2, va1, B0s, B1s, n + 2, 0);
    iterStep(va0, va2, B1s, B0s, n + 3, 0);
    iterStep(va1, va0, B0s, B1s, n + 4, 0);
    iterStep(va2, va1, B1s, B0s, n + 5, 0);
  }
  // ---- tail: last 6 iters with drain
  {
    const int n = niter - 6;
    iterStep(va0, va2, B0s, B1s, n,     0);
    iterStep(va1, va0, B1s, B0s, n + 1, 0);
    iterStep(va2, va1, B0s, B1s, n + 2, 0);
    iterStep(va0, va2, B1s, B0s, n + 3, 0);   // issues A(niter-1)
    iterStep(va1, va0, B0s, B1s, n + 4, 1);   // issues B(niter-1), drains
    iterStep(va2, va1, B1s, B0s, n + 5, 2);   // compute only
  }

  // ---- epilogue: C/D layout col=lane&15, row=(lane>>4)*4+r   [m89]
  float* P = partial + ((size_t)ks * BATCH + m0) * 256;
#pragma unroll
  for (int mf = 0; mf < 2; ++mf) {
    int row = w * 32 + mf * 16 + l4 * 4;
#pragma unroll
    for (int nf = 0; nf < 16; ++nf) {
      int col = nf * 16 + l15;
#pragma unroll
      for (int rr = 0; rr < 4; ++rr)
        P[(size_t)(row + rr) * 256 + col] = acc[mf][nf][rr];
    }
  }
}

// ---------------- tail: partial-reduce + pov mix + relu + fc0..fc3 ----------------
__global__ __launch_bounds__(256)
void nnue_tail(const float* __restrict__ partial, int S,
               const float* __restrict__ pov,
               const float* __restrict__ waffb, const float* __restrict__ baffb,
               const float* __restrict__ fc0W, const float* __restrict__ fc0b,
               const float* __restrict__ fc1W, const float* __restrict__ fc1b,
               const float* __restrict__ fc2W, const float* __restrict__ fc2b,
               const float* __restrict__ fc3W, const float* __restrict__ fc3b,
               float* __restrict__ out) {
  __shared__ float w0s[32 * 256];   // stored at [(j<<8) | ((k+j)&255)]
  __shared__ float w1s[32 * 32];    // [(j<<5) | ((k+j)&31)]
  __shared__ float w2s[32 * 64];    // [(j<<6) | ((k+j)&63)]
  __shared__ float w3s[96];
  __shared__ float b0s[32], b1s[32], b2s[32];
  __shared__ float base_s[4][256];
  __shared__ float b3s;

  const int t = threadIdx.x;
  for (int i = t; i < 8192; i += 256) { int j = i >> 8, k = i & 255; w0s[(j << 8) | ((k + j) & 255)] = fc0W[i]; }
  for (int i = t; i < 1024; i += 256) { int j = i >> 5, k = i & 31;  w1s[(j << 5) | ((k + j) & 31)]  = fc1W[i]; }
  for (int i = t; i < 2048; i += 256) { int j = i >> 6, k = i & 63;  w2s[(j << 6) | ((k + j) & 63)]  = fc2W[i]; }
  if (t < 96) w3s[t] = fc3W[t];
  if (t < 32) { b0s[t] = fc0b[t]; b1s[t] = fc1b[t]; b2s[t] = fc2b[t]; }
  if (t == 0) b3s = fc3b[0];
  __syncthreads();

  const int wid = t >> 6, lane = t & 63;
  const int m = blockIdx.x * 4 + wid;
  const float pv = pov[m];

  float val[4];
  {
    const float* p = partial + (size_t)m * 256 + lane * 4;
    fvec4 a = *(const fvec4*)p;
    for (int s = 1; s < S; ++s) a += *(const fvec4*)(p + (size_t)s * BATCH * 256);
    const int c0 = lane * 4;
#pragma unroll
    for (int j = 0; j < 4; ++j) {
      int c = c0 + j;
      float bias = (c < 128) ? waffb[c] : baffb[c - 128];
      val[j] = a[j] + bias;
    }
  }
#pragma unroll
  for (int j = 0; j < 4; ++j) {
    float other = __shfl(val[j], lane ^ 32, 64);
    if (lane < 32) {
      int c = lane * 4 + j;
      float w = val[j], b = other;
      base_s[wid][c]       = fmaxf(pv * w + (1.f - pv) * b, 0.f);
      base_s[wid][c + 128] = fmaxf(pv * b + (1.f - pv) * w, 0.f);
    }
  }
  __syncthreads();

  const int j = lane & 31, half = lane >> 5;
  const float* bs = &base_s[wid][0];

  float s0 = 0.f;
  for (int k = 0; k < 128; ++k) {
    int kk = half * 128 + k;
    s0 += bs[kk] * w0s[(j << 8) | ((kk + j) & 255)];
  }
  s0 += __shfl(s0, lane ^ 32, 64);
  float x0 = fmaxf(s0 + b0s[j], 0.f);

  float s1 = 0.f;
  for (int k = 0; k < 32; ++k)
    s1 += __shfl(x0, k, 64) * w1s[(j << 5) | ((k + j) & 31)];
  float x1 = fmaxf(s1 + b1s[j], 0.f);

  float s2 = 0.f;
  for (int k = 0; k < 32; ++k) {
    s2 += __shfl(x0, k, 64) * w2s[(j << 6) | ((k + j) & 63)];
    s2 += __shfl(x1, k, 64) * w2s[(j << 6) | ((k + 32 + j) & 63)];
  }
  float x2 = fmaxf(s2 + b2s[j], 0.f);

  float s3 = 0.f;
  for (int k = 0; k < 32; ++k) {
    s3 += __shfl(x0, k, 64) * w3s[k];
    s3 += __shfl(x1, k, 64) * w3s[32 + k];
    s3 += __shfl(x2, k, 64) * w3s[64 + k];
  }
  if (lane == 0) out[m] = s3 + b3s;
}

extern "C" void kernel_launch(void* const* d_in, const int* in_sizes, int n_in,
                              void* d_out, int out_size, void* d_ws, size_t ws_size,
                              hipStream_t stream) {
  const float* pov   = (const float*)d_in[0];
  const float* white = (const float*)d_in[1];
  const float* black = (const float*)d_in[2];
  const float* wW    = (const float*)d_in[3];
  const float* wb    = (const float*)d_in[4];
  const float* bW    = (const float*)d_in[5];
  const float* bb    = (const float*)d_in[6];
  const float* fc0W  = (const float*)d_in[7];
  const float* fc0b  = (const float*)d_in[8];
  const float* fc1W  = (const float*)d_in[9];
  const float* fc1b  = (const float*)d_in[10];
  const float* fc2W  = (const float*)d_in[11];
  const float* fc2b  = (const float*)d_in[12];
  const float* fc3W  = (const float*)d_in[13];
  const float* fc3b  = (const float*)d_in[14];
  float* out = (float*)d_out;

  short* Bprep = (short*)d_ws;
  const size_t BWS_BYTES = (size_t)256 * NUMELK * 2;      // 25,165,824
  float* partial = (float*)((char*)d_ws + BWS_BYTES);
  const size_t PART1 = (size_t)BATCH * 256 * 4;           // 8,388,608

  int S = 8;                                              // 256 blocks = 1/CU
  if (ws_size < BWS_BYTES + 8 * PART1) S = 4;
  if (ws_size < BWS_BYTES + 4 * PART1) S = 2;
  if (ws_size < BWS_BYTES + 2 * PART1) S = 1;

  nnue_prep<<<dim3(6144), 256, 0, stream>>>(wW, bW, Bprep);
  nnue_gemm<<<dim3(32 * S), 512, 0, stream>>>(white, black, Bprep, partial, NUMELK / S, S);
  nnue_tail<<<dim3(BATCH / 4), 256, 0, stream>>>(partial, S, pov, wb, bb,
      fc0W, fc0b, fc1W, fc1b, fc2W, fc2b, fc3W, fc3b, out);
}